// Round 6
// baseline (282.688 us; speedup 1.0000x reference)
//
#include <hip/hip_runtime.h>

#define Hd 512
#define N2d 16
#define Rd 32
#define Ld 4096
#define NCHUNK 128
#define CLEN (Ld / NCHUNK)        // 32
#define NCH (Hd * N2d)            // 8192 chains
#define NGRP 16                   // chunks per prefix group
#define NGROUPS (NCHUNK / NGRP)   // 8

// ---------------------------------------------------------------------------
// Per-thread constant setup: 4 consecutive n of one h. fast == true when Are
// uniform and Aim arithmetic across the 4 (true for S4D init A = -1 + i*n).
// ---------------------------------------------------------------------------
__device__ __forceinline__ bool load_consts4(const float* A_log, const float* A_im,
        const float* B_param, int hnb,
        float* Are, float* Aim, float* BAr, float* BAi) {
    #pragma unroll
    for (int j = 0; j < 4; ++j) {
        int hn = hnb + j;
        Are[j] = -__expf(A_log[hn]);
        Aim[j] = A_im[hn];
        float Bre = B_param[2 * hn];
        float Bim = B_param[2 * hn + 1];
        float inv = __builtin_amdgcn_rcpf(Are[j] * Are[j] + Aim[j] * Aim[j]);
        BAr[j] = (Bre * Are[j] + Bim * Aim[j]) * inv;   // Bc*conj(A)/|A|^2
        BAi[j] = (Bim * Are[j] - Bre * Aim[j]) * inv;
    }
    float d1 = Aim[1] - Aim[0], d2 = Aim[2] - Aim[1], d3 = Aim[3] - Aim[2];
    return (Are[1] == Are[0]) && (Are[2] == Are[0]) && (Are[3] == Are[0]) &&
           (d1 == d2) && (d2 == d3);
}

// ---------------------------------------------------------------------------
// Kernel 1: dt = softplus(u@xprojT@dtwT + b); writes du[l][h] = (dt, u/dt).
// ---------------------------------------------------------------------------
__global__ __launch_bounds__(256) void k_dt(const float* __restrict__ u,
                                            const float* __restrict__ xproj_w,
                                            const float* __restrict__ dt_w,
                                            const float* __restrict__ dt_b,
                                            float2* __restrict__ du_out) {
    __shared__ float u_s[8][Hd];
    __shared__ float dtu_s[8][Rd];
    const int t = threadIdx.x;
    const int l0 = blockIdx.x * 8;

    #pragma unroll
    for (int i = 0; i < 16; ++i) {
        int idx = t + i * 256;
        ((float*)u_s)[idx] = u[l0 * Hd + idx];
    }
    __syncthreads();

    const int r = t >> 3;
    const int j = t & 7;
    float part[8];
    #pragma unroll
    for (int l = 0; l < 8; ++l) part[l] = 0.f;
    for (int k = 0; k < 64; ++k) {
        float w = xproj_w[r * Hd + k * 8 + j];
        #pragma unroll
        for (int l = 0; l < 8; ++l) part[l] = fmaf(u_s[l][k * 8 + j], w, part[l]);
    }
    #pragma unroll
    for (int off = 1; off < 8; off <<= 1) {
        #pragma unroll
        for (int l = 0; l < 8; ++l) part[l] += __shfl_xor(part[l], off);
    }
    if (j == 0) {
        #pragma unroll
        for (int l = 0; l < 8; ++l) dtu_s[l][r] = part[l];
    }
    __syncthreads();

    #pragma unroll
    for (int hb = 0; hb < 2; ++hb) {
        int h = hb * 256 + t;
        float bias = dt_b[h];
        float acc[8];
        #pragma unroll
        for (int l = 0; l < 8; ++l) acc[l] = bias;
        #pragma unroll
        for (int rb = 0; rb < 8; ++rb) {
            float4 w = *(const float4*)&dt_w[h * Rd + rb * 4];
            #pragma unroll
            for (int l = 0; l < 8; ++l) {
                acc[l] = fmaf(dtu_s[l][rb * 4 + 0], w.x, acc[l]);
                acc[l] = fmaf(dtu_s[l][rb * 4 + 1], w.y, acc[l]);
                acc[l] = fmaf(dtu_s[l][rb * 4 + 2], w.z, acc[l]);
                acc[l] = fmaf(dtu_s[l][rb * 4 + 3], w.w, acc[l]);
            }
        }
        #pragma unroll
        for (int l = 0; l < 8; ++l) {
            float x = acc[l];
            float sp = fmaxf(x, 0.f) + log1pf(__expf(-fabsf(x)));  // softplus
            float uv = u_s[l][h];
            float us = uv * __builtin_amdgcn_rcpf(fmaxf(sp, 1e-30f));
            du_out[(l0 + l) * Hd + h] = make_float2(sp, us);
        }
    }
}

// ---------------------------------------------------------------------------
// Kernel 2: per-chunk local scan (h0=0). Emits:
//   PS[c][chain] = (P.re, P.im, S.re, S.im)     (chunk aggregate)
//   y1T[l][h]    = (Re(C*S_local_l) + D*u_l, T_l)  (partial y + inclusive sum-dt)
// The correction pass reconstructs the full y from y1T without re-scanning:
//   y_l = y1_l + Re(sum_n C_n * exp(A_n*T_l) * h0_n)
// ---------------------------------------------------------------------------
__global__ __launch_bounds__(256) void k_chunk(const float2* __restrict__ du,
        const float* __restrict__ A_log, const float* __restrict__ A_im,
        const float* __restrict__ B_param, const float* __restrict__ C_param,
        const float* __restrict__ Dp,
        float4* __restrict__ PS, float2* __restrict__ y1T) {
    const int t = threadIdx.x;
    const int q = t & 3;
    const int hh = blockIdx.y * 64 + (t >> 2);
    const int c = blockIdx.x;
    const int hnb = hh * N2d + q * 4;
    const int lbase = c * CLEN;

    float2 d0[16], d1[16];
    #pragma unroll
    for (int k = 0; k < 16; ++k) d0[k] = du[(lbase + k) * Hd + hh];
    #pragma unroll
    for (int k = 0; k < 16; ++k) d1[k] = du[(lbase + 16 + k) * Hd + hh];

    float Are[4], Aim[4], BAr[4], BAi[4], Cre[4], Cim[4];
    const bool fast = load_consts4(A_log, A_im, B_param, hnb, Are, Aim, BAr, BAi);
    #pragma unroll
    for (int jj = 0; jj < 4; ++jj) {
        Cre[jj] = C_param[2 * (hnb + jj)];
        Cim[jj] = C_param[2 * (hnb + jj) + 1];
    }
    const float Dv = Dp[hh];

    float sr[4] = {0.f, 0.f, 0.f, 0.f}, si[4] = {0.f, 0.f, 0.f, 0.f};
    float sdt = 0.f;
    if (fast) {
        const float Are0 = Are[0], Aim0 = Aim[0], dA = Aim[1] - Aim[0];
        #pragma unroll
        for (int half = 0; half < 2; ++half) {
            #pragma unroll
            for (int k = 0; k < 16; ++k) {
                int l = lbase + half * 16 + k;
                float2 d = half ? d1[k] : d0[k];
                float dtv = d.x, us = d.y;
                sdt += dtv;                     // inclusive T_l
                float er = __expf(dtv * Are0);
                float s0, c0, sd, cd;
                __sincosf(dtv * Aim0, &s0, &c0);
                __sincosf(dtv * dA, &sd, &cd);
                float ar = er * c0, ai = er * s0;
                float yv = 0.f;
                #pragma unroll
                for (int jj = 0; jj < 4; ++jj) {
                    float gr = fmaf(ar, us, -us);
                    float gi = ai * us;
                    float nr = fmaf(ar, sr[jj], fmaf(-ai, si[jj], fmaf(gr, BAr[jj], -gi * BAi[jj])));
                    float ni = fmaf(ar, si[jj], fmaf( ai, sr[jj], fmaf(gr, BAi[jj],  gi * BAr[jj])));
                    sr[jj] = nr; si[jj] = ni;
                    yv = fmaf(nr, Cre[jj], fmaf(-ni, Cim[jj], yv));
                    if (jj < 3) {
                        float tr = fmaf(ar, cd, -ai * sd);
                        ai = fmaf(ai, cd, ar * sd);
                        ar = tr;
                    }
                }
                yv += __shfl_xor(yv, 1);
                yv += __shfl_xor(yv, 2);
                if (q == 0) y1T[l * Hd + hh] = make_float2(fmaf(dtv * us, Dv, yv), sdt);
            }
        }
    } else {
        #pragma unroll
        for (int half = 0; half < 2; ++half) {
            #pragma unroll
            for (int k = 0; k < 16; ++k) {
                int l = lbase + half * 16 + k;
                float2 d = half ? d1[k] : d0[k];
                float dtv = d.x, us = d.y;
                sdt += dtv;
                float yv = 0.f;
                #pragma unroll
                for (int jj = 0; jj < 4; ++jj) {
                    float er = __expf(dtv * Are[jj]);
                    float s, cc;
                    __sincosf(dtv * Aim[jj], &s, &cc);
                    float ar = er * cc, ai = er * s;
                    float gr = fmaf(ar, us, -us);
                    float gi = ai * us;
                    float nr = fmaf(ar, sr[jj], fmaf(-ai, si[jj], fmaf(gr, BAr[jj], -gi * BAi[jj])));
                    float ni = fmaf(ar, si[jj], fmaf( ai, sr[jj], fmaf(gr, BAi[jj],  gi * BAr[jj])));
                    sr[jj] = nr; si[jj] = ni;
                    yv = fmaf(nr, Cre[jj], fmaf(-ni, Cim[jj], yv));
                }
                yv += __shfl_xor(yv, 1);
                yv += __shfl_xor(yv, 2);
                if (q == 0) y1T[l * Hd + hh] = make_float2(fmaf(dtv * us, Dv, yv), sdt);
            }
        }
    }
    int base = c * NCH + hnb;
    #pragma unroll
    for (int jj = 0; jj < 4; ++jj) {
        float er = __expf(sdt * Are[jj]);
        float s, cc;
        __sincosf(sdt * Aim[jj], &s, &cc);
        PS[base + jj] = make_float4(er * cc, er * s, sr[jj], si[jj]);
    }
}

// ---------------------------------------------------------------------------
// Kernel 3a: per-(chain, group) combine over NGRP=16 chunks.
// Writes EXCLUSIVE in-group prefix IP[c] = (Pcum, Ilocal) and group agg Gps.
// ---------------------------------------------------------------------------
__global__ __launch_bounds__(256) void k_group(const float4* __restrict__ PS,
                                               float4* __restrict__ IP,
                                               float4* __restrict__ Gps) {
    int idx = blockIdx.x * 256 + threadIdx.x;   // 0..65535
    int chain = idx & (NCH - 1);
    int g = idx >> 13;                          // 0..7
    float pr = 1.f, pi = 0.f, hr = 0.f, hi = 0.f;
    #pragma unroll
    for (int half = 0; half < 2; ++half) {
        float4 ps[8];
        #pragma unroll
        for (int i = 0; i < 8; ++i)
            ps[i] = PS[(g * NGRP + half * 8 + i) * NCH + chain];
        #pragma unroll
        for (int i = 0; i < 8; ++i) {
            int c = g * NGRP + half * 8 + i;
            IP[c * NCH + chain] = make_float4(pr, pi, hr, hi);
            float nhr = fmaf(ps[i].x, hr, fmaf(-ps[i].y, hi, ps[i].z));
            float nhi = fmaf(ps[i].x, hi, fmaf( ps[i].y, hr, ps[i].w));
            float npr = fmaf(ps[i].x, pr, -ps[i].y * pi);
            float npi = fmaf(ps[i].x, pi,  ps[i].y * pr);
            hr = nhr; hi = nhi; pr = npr; pi = npi;
        }
    }
    Gps[g * NCH + chain] = make_float4(pr, pi, hr, hi);
}

// ---------------------------------------------------------------------------
// Kernel 3b: exclusive scan of the 8 group aggregates per chain -> H0g.
// ---------------------------------------------------------------------------
__global__ __launch_bounds__(256) void k_gscan(const float4* __restrict__ Gps,
                                               float2* __restrict__ H0g) {
    int chain = blockIdx.x * 256 + threadIdx.x;  // 0..8191
    float4 gp[NGROUPS];
    #pragma unroll
    for (int i = 0; i < NGROUPS; ++i)
        gp[i] = Gps[i * NCH + chain];
    float hr = 0.f, hi = 0.f;
    #pragma unroll
    for (int i = 0; i < NGROUPS; ++i) {
        H0g[i * NCH + chain] = make_float2(hr, hi);
        float nr = fmaf(gp[i].x, hr, fmaf(-gp[i].y, hi, gp[i].z));
        float ni = fmaf(gp[i].x, hi, fmaf( gp[i].y, hr, gp[i].w));
        hr = nr; hi = ni;
    }
}

// ---------------------------------------------------------------------------
// Kernel 4: correction pass — NO serial recurrence. One thread per (l,h):
//   h0_n = Ilocal_n + Pcum_n * H0g_n          (chunk-init state)
//   y    = y1 + Re( sum_n C_n * exp(A_n*T_l) * h0_n )
// Fully parallel, coalesced float2 in / float out.
// ---------------------------------------------------------------------------
__global__ __launch_bounds__(256) void k_corr(const float2* __restrict__ y1T,
        const float* __restrict__ A_log, const float* __restrict__ A_im,
        const float* __restrict__ C_param, const float4* __restrict__ IP,
        const float2* __restrict__ H0g, float* __restrict__ out) {
    int gid = blockIdx.x * 256 + threadIdx.x;     // 0 .. L*Hd-1
    int h = gid & (Hd - 1);
    int l = gid >> 9;
    int c = l >> 5;                               // CLEN = 32
    int g = c >> 4;                               // NGRP = 16
    int hn0 = h * N2d;

    float2 yt = y1T[gid];
    float T = yt.y;

    float Are[N2d], Aim[N2d];
    #pragma unroll
    for (int n = 0; n < N2d; ++n) {
        Are[n] = -__expf(A_log[hn0 + n]);
        Aim[n] = A_im[hn0 + n];
    }
    float dA = Aim[1] - Aim[0];
    bool fast = true;
    #pragma unroll
    for (int n = 1; n < N2d; ++n)
        fast = fast && (Are[n] == Are[0]) && (Aim[n] - Aim[n - 1] == dA);

    float corr = 0.f;
    if (fast) {
        float er = __expf(Are[0] * T);
        float s0, c0, sd, cd;
        __sincosf(Aim[0] * T, &s0, &c0);
        __sincosf(dA * T, &sd, &cd);
        float ar = er * c0, ai = er * s0;
        #pragma unroll
        for (int n = 0; n < N2d; ++n) {
            float4 ip = IP[c * NCH + hn0 + n];           // (Pcum, Ilocal)
            float2 hg = H0g[g * NCH + hn0 + n];
            float h0r = fmaf(ip.x, hg.x, fmaf(-ip.y, hg.y, ip.z));
            float h0i = fmaf(ip.x, hg.y, fmaf( ip.y, hg.x, ip.w));
            float Cr = C_param[2 * (hn0 + n)];
            float Ci = C_param[2 * (hn0 + n) + 1];
            float wr = fmaf(Cr, h0r, -Ci * h0i);
            float wi = fmaf(Cr, h0i,  Ci * h0r);
            corr = fmaf(ar, wr, fmaf(-ai, wi, corr));    // Re(exp * w)
            if (n < N2d - 1) {
                float tr = fmaf(ar, cd, -ai * sd);
                ai = fmaf(ai, cd, ar * sd);
                ar = tr;
            }
        }
    } else {
        #pragma unroll
        for (int n = 0; n < N2d; ++n) {
            float4 ip = IP[c * NCH + hn0 + n];
            float2 hg = H0g[g * NCH + hn0 + n];
            float h0r = fmaf(ip.x, hg.x, fmaf(-ip.y, hg.y, ip.z));
            float h0i = fmaf(ip.x, hg.y, fmaf( ip.y, hg.x, ip.w));
            float Cr = C_param[2 * (hn0 + n)];
            float Ci = C_param[2 * (hn0 + n) + 1];
            float wr = fmaf(Cr, h0r, -Ci * h0i);
            float wi = fmaf(Cr, h0i,  Ci * h0r);
            float er = __expf(Are[n] * T);
            float s, cc;
            __sincosf(Aim[n] * T, &s, &cc);
            corr = fmaf(er * cc, wr, fmaf(-er * s, wi, corr));
        }
    }
    out[gid] = yt.x + corr;
}

extern "C" void kernel_launch(void* const* d_in, const int* in_sizes, int n_in,
                              void* d_out, int out_size, void* d_ws, size_t ws_size,
                              hipStream_t stream) {
    const float* u        = (const float*)d_in[0];
    const float* A_log    = (const float*)d_in[1];
    const float* A_im     = (const float*)d_in[2];
    const float* B_param  = (const float*)d_in[3];
    const float* C_param  = (const float*)d_in[4];
    const float* Dp       = (const float*)d_in[5];
    const float* dt_w     = (const float*)d_in[6];
    const float* dt_b     = (const float*)d_in[7];
    const float* xproj_w  = (const float*)d_in[8];

    // ws layout: du[L*H f2] | PS[NCHUNK*NCH f4] | IP[NCHUNK*NCH f4]
    //          | Gps[NGROUPS*NCH f4] | H0g[NGROUPS*NCH f2] | y1T[L*H f2]
    float2* du  = (float2*)d_ws;
    float4* PS  = (float4*)(du + (size_t)Ld * Hd);
    float4* IP  = PS + (size_t)NCHUNK * NCH;
    float4* Gps = IP + (size_t)NCHUNK * NCH;
    float2* H0g = (float2*)(Gps + (size_t)NGROUPS * NCH);
    float2* y1T = H0g + (size_t)NGROUPS * NCH;
    float*  out = (float*)d_out;

    k_dt<<<Ld / 8, 256, 0, stream>>>(u, xproj_w, dt_w, dt_b, du);
    dim3 g2(NCHUNK, Hd / 64);
    k_chunk<<<g2, 256, 0, stream>>>(du, A_log, A_im, B_param, C_param, Dp, PS, y1T);
    k_group<<<(NCH * NGROUPS) / 256, 256, 0, stream>>>(PS, IP, Gps);
    k_gscan<<<NCH / 256, 256, 0, stream>>>(Gps, H0g);
    k_corr<<<(Ld * Hd) / 256, 256, 0, stream>>>(y1T, A_log, A_im, C_param,
                                                IP, H0g, out);
}

// Round 7
// 145.004 us; speedup vs baseline: 1.9495x; 1.9495x over previous
//
#include <hip/hip_runtime.h>

#define Hd 512
#define N2d 16
#define Rd 32
#define Ld 4096
#define NCHUNK 128
#define CLEN (Ld / NCHUNK)        // 32
#define NCH (Hd * N2d)            // 8192 chains
#define NGRP 16                   // chunks per prefix group
#define NGROUPS (NCHUNK / NGRP)   // 8

// ---------------------------------------------------------------------------
// Per-thread constant setup: 4 consecutive n of one h. fast == true when Are
// uniform and Aim arithmetic across the 4 (true for S4D init A = -1 + i*n).
// ---------------------------------------------------------------------------
__device__ __forceinline__ bool load_consts4(const float* A_log, const float* A_im,
        const float* B_param, int hnb,
        float* Are, float* Aim, float* BAr, float* BAi) {
    #pragma unroll
    for (int j = 0; j < 4; ++j) {
        int hn = hnb + j;
        Are[j] = -__expf(A_log[hn]);
        Aim[j] = A_im[hn];
        float Bre = B_param[2 * hn];
        float Bim = B_param[2 * hn + 1];
        float inv = __builtin_amdgcn_rcpf(Are[j] * Are[j] + Aim[j] * Aim[j]);
        BAr[j] = (Bre * Are[j] + Bim * Aim[j]) * inv;   // Bc*conj(A)/|A|^2
        BAi[j] = (Bim * Are[j] - Bre * Aim[j]) * inv;
    }
    float d1 = Aim[1] - Aim[0], d2 = Aim[2] - Aim[1], d3 = Aim[3] - Aim[2];
    return (Are[1] == Are[0]) && (Are[2] == Are[0]) && (Are[3] == Are[0]) &&
           (d1 == d2) && (d2 == d3);
}

// ---------------------------------------------------------------------------
// Kernel 1: dt = softplus(u@xprojT@dtwT + b); writes du[l][h] = (dt, u/dt).
// ---------------------------------------------------------------------------
__global__ __launch_bounds__(256) void k_dt(const float* __restrict__ u,
                                            const float* __restrict__ xproj_w,
                                            const float* __restrict__ dt_w,
                                            const float* __restrict__ dt_b,
                                            float2* __restrict__ du_out) {
    __shared__ float u_s[8][Hd];
    __shared__ float dtu_s[8][Rd];
    const int t = threadIdx.x;
    const int l0 = blockIdx.x * 8;

    #pragma unroll
    for (int i = 0; i < 16; ++i) {
        int idx = t + i * 256;
        ((float*)u_s)[idx] = u[l0 * Hd + idx];
    }
    __syncthreads();

    const int r = t >> 3;
    const int j = t & 7;
    float part[8];
    #pragma unroll
    for (int l = 0; l < 8; ++l) part[l] = 0.f;
    for (int k = 0; k < 64; ++k) {
        float w = xproj_w[r * Hd + k * 8 + j];
        #pragma unroll
        for (int l = 0; l < 8; ++l) part[l] = fmaf(u_s[l][k * 8 + j], w, part[l]);
    }
    #pragma unroll
    for (int off = 1; off < 8; off <<= 1) {
        #pragma unroll
        for (int l = 0; l < 8; ++l) part[l] += __shfl_xor(part[l], off);
    }
    if (j == 0) {
        #pragma unroll
        for (int l = 0; l < 8; ++l) dtu_s[l][r] = part[l];
    }
    __syncthreads();

    #pragma unroll
    for (int hb = 0; hb < 2; ++hb) {
        int h = hb * 256 + t;
        float bias = dt_b[h];
        float acc[8];
        #pragma unroll
        for (int l = 0; l < 8; ++l) acc[l] = bias;
        #pragma unroll
        for (int rb = 0; rb < 8; ++rb) {
            float4 w = *(const float4*)&dt_w[h * Rd + rb * 4];
            #pragma unroll
            for (int l = 0; l < 8; ++l) {
                acc[l] = fmaf(dtu_s[l][rb * 4 + 0], w.x, acc[l]);
                acc[l] = fmaf(dtu_s[l][rb * 4 + 1], w.y, acc[l]);
                acc[l] = fmaf(dtu_s[l][rb * 4 + 2], w.z, acc[l]);
                acc[l] = fmaf(dtu_s[l][rb * 4 + 3], w.w, acc[l]);
            }
        }
        #pragma unroll
        for (int l = 0; l < 8; ++l) {
            float x = acc[l];
            float sp = fmaxf(x, 0.f) + log1pf(__expf(-fabsf(x)));  // softplus
            float uv = u_s[l][h];
            float us = uv * __builtin_amdgcn_rcpf(fmaxf(sp, 1e-30f));
            du_out[(l0 + l) * Hd + h] = make_float2(sp, us);
        }
    }
}

// ---------------------------------------------------------------------------
// Kernel 2: per-chunk local scan (h0=0). Emits:
//   PS[c][chain] = (P.re, P.im, S.re, S.im)        (chunk aggregate)
//   y1T[l][h]    = (Re(C*S_local_l) + D*u_l, T_l)  (partial y + incl. sum-dt)
// ---------------------------------------------------------------------------
__global__ __launch_bounds__(256) void k_chunk(const float2* __restrict__ du,
        const float* __restrict__ A_log, const float* __restrict__ A_im,
        const float* __restrict__ B_param, const float* __restrict__ C_param,
        const float* __restrict__ Dp,
        float4* __restrict__ PS, float2* __restrict__ y1T) {
    const int t = threadIdx.x;
    const int q = t & 3;
    const int hh = blockIdx.y * 64 + (t >> 2);
    const int c = blockIdx.x;
    const int hnb = hh * N2d + q * 4;
    const int lbase = c * CLEN;

    float2 d0[16], d1[16];
    #pragma unroll
    for (int k = 0; k < 16; ++k) d0[k] = du[(lbase + k) * Hd + hh];
    #pragma unroll
    for (int k = 0; k < 16; ++k) d1[k] = du[(lbase + 16 + k) * Hd + hh];

    float Are[4], Aim[4], BAr[4], BAi[4], Cre[4], Cim[4];
    const bool fast = load_consts4(A_log, A_im, B_param, hnb, Are, Aim, BAr, BAi);
    #pragma unroll
    for (int jj = 0; jj < 4; ++jj) {
        Cre[jj] = C_param[2 * (hnb + jj)];
        Cim[jj] = C_param[2 * (hnb + jj) + 1];
    }
    const float Dv = Dp[hh];

    float sr[4] = {0.f, 0.f, 0.f, 0.f}, si[4] = {0.f, 0.f, 0.f, 0.f};
    float sdt = 0.f;
    if (fast) {
        const float Are0 = Are[0], Aim0 = Aim[0], dA = Aim[1] - Aim[0];
        #pragma unroll
        for (int half = 0; half < 2; ++half) {
            #pragma unroll
            for (int k = 0; k < 16; ++k) {
                int l = lbase + half * 16 + k;
                float2 d = half ? d1[k] : d0[k];
                float dtv = d.x, us = d.y;
                sdt += dtv;                     // inclusive T_l
                float er = __expf(dtv * Are0);
                float s0, c0, sd, cd;
                __sincosf(dtv * Aim0, &s0, &c0);
                __sincosf(dtv * dA, &sd, &cd);
                float ar = er * c0, ai = er * s0;
                float yv = 0.f;
                #pragma unroll
                for (int jj = 0; jj < 4; ++jj) {
                    float gr = fmaf(ar, us, -us);
                    float gi = ai * us;
                    float nr = fmaf(ar, sr[jj], fmaf(-ai, si[jj], fmaf(gr, BAr[jj], -gi * BAi[jj])));
                    float ni = fmaf(ar, si[jj], fmaf( ai, sr[jj], fmaf(gr, BAi[jj],  gi * BAr[jj])));
                    sr[jj] = nr; si[jj] = ni;
                    yv = fmaf(nr, Cre[jj], fmaf(-ni, Cim[jj], yv));
                    if (jj < 3) {
                        float tr = fmaf(ar, cd, -ai * sd);
                        ai = fmaf(ai, cd, ar * sd);
                        ar = tr;
                    }
                }
                yv += __shfl_xor(yv, 1);
                yv += __shfl_xor(yv, 2);
                if (q == 0) y1T[l * Hd + hh] = make_float2(fmaf(dtv * us, Dv, yv), sdt);
            }
        }
    } else {
        #pragma unroll
        for (int half = 0; half < 2; ++half) {
            #pragma unroll
            for (int k = 0; k < 16; ++k) {
                int l = lbase + half * 16 + k;
                float2 d = half ? d1[k] : d0[k];
                float dtv = d.x, us = d.y;
                sdt += dtv;
                float yv = 0.f;
                #pragma unroll
                for (int jj = 0; jj < 4; ++jj) {
                    float er = __expf(dtv * Are[jj]);
                    float s, cc;
                    __sincosf(dtv * Aim[jj], &s, &cc);
                    float ar = er * cc, ai = er * s;
                    float gr = fmaf(ar, us, -us);
                    float gi = ai * us;
                    float nr = fmaf(ar, sr[jj], fmaf(-ai, si[jj], fmaf(gr, BAr[jj], -gi * BAi[jj])));
                    float ni = fmaf(ar, si[jj], fmaf( ai, sr[jj], fmaf(gr, BAi[jj],  gi * BAr[jj])));
                    sr[jj] = nr; si[jj] = ni;
                    yv = fmaf(nr, Cre[jj], fmaf(-ni, Cim[jj], yv));
                }
                yv += __shfl_xor(yv, 1);
                yv += __shfl_xor(yv, 2);
                if (q == 0) y1T[l * Hd + hh] = make_float2(fmaf(dtv * us, Dv, yv), sdt);
            }
        }
    }
    int base = c * NCH + hnb;
    #pragma unroll
    for (int jj = 0; jj < 4; ++jj) {
        float er = __expf(sdt * Are[jj]);
        float s, cc;
        __sincosf(sdt * Aim[jj], &s, &cc);
        PS[base + jj] = make_float4(er * cc, er * s, sr[jj], si[jj]);
    }
}

// ---------------------------------------------------------------------------
// Kernel 3a: per-(chain, group) combine over NGRP=16 chunks.
// Writes EXCLUSIVE in-group prefix IP[c] = (Pcum, Ilocal) and group agg Gps.
// ---------------------------------------------------------------------------
__global__ __launch_bounds__(256) void k_group(const float4* __restrict__ PS,
                                               float4* __restrict__ IP,
                                               float4* __restrict__ Gps) {
    int idx = blockIdx.x * 256 + threadIdx.x;   // 0..65535
    int chain = idx & (NCH - 1);
    int g = idx >> 13;                          // 0..7
    float pr = 1.f, pi = 0.f, hr = 0.f, hi = 0.f;
    #pragma unroll
    for (int half = 0; half < 2; ++half) {
        float4 ps[8];
        #pragma unroll
        for (int i = 0; i < 8; ++i)
            ps[i] = PS[(g * NGRP + half * 8 + i) * NCH + chain];
        #pragma unroll
        for (int i = 0; i < 8; ++i) {
            int c = g * NGRP + half * 8 + i;
            IP[c * NCH + chain] = make_float4(pr, pi, hr, hi);
            float nhr = fmaf(ps[i].x, hr, fmaf(-ps[i].y, hi, ps[i].z));
            float nhi = fmaf(ps[i].x, hi, fmaf( ps[i].y, hr, ps[i].w));
            float npr = fmaf(ps[i].x, pr, -ps[i].y * pi);
            float npi = fmaf(ps[i].x, pi,  ps[i].y * pr);
            hr = nhr; hi = nhi; pr = npr; pi = npi;
        }
    }
    Gps[g * NCH + chain] = make_float4(pr, pi, hr, hi);
}

// ---------------------------------------------------------------------------
// Kernel 3b: exclusive scan of the 8 group aggregates per chain -> H0g.
// ---------------------------------------------------------------------------
__global__ __launch_bounds__(256) void k_gscan(const float4* __restrict__ Gps,
                                               float2* __restrict__ H0g) {
    int chain = blockIdx.x * 256 + threadIdx.x;  // 0..8191
    float4 gp[NGROUPS];
    #pragma unroll
    for (int i = 0; i < NGROUPS; ++i)
        gp[i] = Gps[i * NCH + chain];
    float hr = 0.f, hi = 0.f;
    #pragma unroll
    for (int i = 0; i < NGROUPS; ++i) {
        H0g[i * NCH + chain] = make_float2(hr, hi);
        float nr = fmaf(gp[i].x, hr, fmaf(-gp[i].y, hi, gp[i].z));
        float ni = fmaf(gp[i].x, hi, fmaf( gp[i].y, hr, gp[i].w));
        hr = nr; hi = ni;
    }
}

// ---------------------------------------------------------------------------
// Kernel 4: correction pass. Block = (chunk c, 64-h group). Stages the
// per-(c,chain) weight W = C*(Ilocal + Pcum*H0g) into LDS ONCE (coalesced,
// reused by all 32 l's), plus Are/Aim rows. Each thread owns one h (lane=h ->
// coalesced y1T/out) x 8 l's with W-row/A-row hoisted into registers:
//   y = y1 + Re( sum_n exp(A_n*T_l) * W_n )
// ---------------------------------------------------------------------------
__global__ __launch_bounds__(256) void k_corr(const float2* __restrict__ y1T,
        const float* __restrict__ A_log, const float* __restrict__ A_im,
        const float* __restrict__ C_param, const float4* __restrict__ IP,
        const float2* __restrict__ H0g, float* __restrict__ out) {
    __shared__ float2 W_s[64][17];   // [h_local][n], pad -> 2-way (free)
    __shared__ float Ar_s[64][17];
    __shared__ float Ai_s[64][17];
    const int t = threadIdx.x;
    const int c = blockIdx.x;        // chunk
    const int hg = blockIdx.y;       // h-group (64 h)
    const int g = c >> 4;            // NGRP = 16
    const int chain0 = hg * 1024;    // 64 h * 16 n contiguous chains

    // ---- cooperative staging: 4 contiguous chains per thread ----
    #pragma unroll
    for (int i = 0; i < 4; ++i) {
        int cl = t * 4 + i;                       // 0..1023
        float4 ip = IP[c * NCH + chain0 + cl];    // (Pcum, Ilocal)
        float2 hgv = H0g[g * NCH + chain0 + cl];
        float h0r = fmaf(ip.x, hgv.x, fmaf(-ip.y, hgv.y, ip.z));
        float h0i = fmaf(ip.x, hgv.y, fmaf( ip.y, hgv.x, ip.w));
        float Cr = C_param[2 * (chain0 + cl)];
        float Ci = C_param[2 * (chain0 + cl) + 1];
        int hl = cl >> 4, n = cl & 15;
        W_s[hl][n] = make_float2(fmaf(Cr, h0r, -Ci * h0i),
                                 fmaf(Cr, h0i,  Ci * h0r));
        Ar_s[hl][n] = -__expf(A_log[chain0 + cl]);
        Ai_s[hl][n] = A_im[chain0 + cl];
    }
    __syncthreads();

    // ---- per-thread: one h, 8 l's ----
    const int hl = t & 63;
    const int h = hg * 64 + hl;
    const int lb = t >> 6;                        // 0..3
    const int l0 = c * CLEN + lb * 8;

    float2 w[N2d];
    float are[N2d], aim[N2d];
    #pragma unroll
    for (int n = 0; n < N2d; ++n) {
        w[n] = W_s[hl][n];
        are[n] = Ar_s[hl][n];
        aim[n] = Ai_s[hl][n];
    }
    float dA = aim[1] - aim[0];
    bool fast = true;
    #pragma unroll
    for (int n = 1; n < N2d; ++n)
        fast = fast && (are[n] == are[0]) && (aim[n] - aim[n - 1] == dA);

    if (fast) {
        const float Are0 = are[0], Aim0 = aim[0];
        #pragma unroll
        for (int k = 0; k < 8; ++k) {
            int l = l0 + k;
            float2 yt = y1T[l * Hd + h];
            float T = yt.y;
            float er = __expf(Are0 * T);
            float s0, c0, sd, cd;
            __sincosf(Aim0 * T, &s0, &c0);
            __sincosf(dA * T, &sd, &cd);
            float ar = er * c0, ai = er * s0;
            float corr = 0.f;
            #pragma unroll
            for (int n = 0; n < N2d; ++n) {
                corr = fmaf(ar, w[n].x, fmaf(-ai, w[n].y, corr));
                if (n < N2d - 1) {
                    float tr = fmaf(ar, cd, -ai * sd);
                    ai = fmaf(ai, cd, ar * sd);
                    ar = tr;
                }
            }
            out[l * Hd + h] = yt.x + corr;
        }
    } else {
        #pragma unroll
        for (int k = 0; k < 8; ++k) {
            int l = l0 + k;
            float2 yt = y1T[l * Hd + h];
            float T = yt.y;
            float corr = 0.f;
            #pragma unroll
            for (int n = 0; n < N2d; ++n) {
                float er = __expf(are[n] * T);
                float s, cc;
                __sincosf(aim[n] * T, &s, &cc);
                corr = fmaf(er * cc, w[n].x, fmaf(-er * s, w[n].y, corr));
            }
            out[l * Hd + h] = yt.x + corr;
        }
    }
}

extern "C" void kernel_launch(void* const* d_in, const int* in_sizes, int n_in,
                              void* d_out, int out_size, void* d_ws, size_t ws_size,
                              hipStream_t stream) {
    const float* u        = (const float*)d_in[0];
    const float* A_log    = (const float*)d_in[1];
    const float* A_im     = (const float*)d_in[2];
    const float* B_param  = (const float*)d_in[3];
    const float* C_param  = (const float*)d_in[4];
    const float* Dp       = (const float*)d_in[5];
    const float* dt_w     = (const float*)d_in[6];
    const float* dt_b     = (const float*)d_in[7];
    const float* xproj_w  = (const float*)d_in[8];

    // ws layout: du[L*H f2] | PS[NCHUNK*NCH f4] | IP[NCHUNK*NCH f4]
    //          | Gps[NGROUPS*NCH f4] | H0g[NGROUPS*NCH f2] | y1T[L*H f2]
    float2* du  = (float2*)d_ws;
    float4* PS  = (float4*)(du + (size_t)Ld * Hd);
    float4* IP  = PS + (size_t)NCHUNK * NCH;
    float4* Gps = IP + (size_t)NCHUNK * NCH;
    float2* H0g = (float2*)(Gps + (size_t)NGROUPS * NCH);
    float2* y1T = H0g + (size_t)NGROUPS * NCH;
    float*  out = (float*)d_out;

    k_dt<<<Ld / 8, 256, 0, stream>>>(u, xproj_w, dt_w, dt_b, du);
    dim3 g2(NCHUNK, Hd / 64);
    k_chunk<<<g2, 256, 0, stream>>>(du, A_log, A_im, B_param, C_param, Dp, PS, y1T);
    k_group<<<(NCH * NGROUPS) / 256, 256, 0, stream>>>(PS, IP, Gps);
    k_gscan<<<NCH / 256, 256, 0, stream>>>(Gps, H0g);
    k_corr<<<g2, 256, 0, stream>>>(y1T, A_log, A_im, C_param, IP, H0g, out);
}

// Round 8
// 139.242 us; speedup vs baseline: 2.0302x; 1.0414x over previous
//
#include <hip/hip_runtime.h>

#define Hd 512
#define N2d 16
#define Rd 32
#define Ld 4096
#define NCHUNK 128
#define CLEN (Ld / NCHUNK)        // 32
#define NCH (Hd * N2d)            // 8192 chains
#define NGRP 16                   // chunks per prefix group
#define NGROUPS (NCHUNK / NGRP)   // 8

// ---------------------------------------------------------------------------
// Per-thread constant setup: 4 consecutive n of one h. fast == true when Are
// uniform and Aim arithmetic across the 4 (true for S4D init A = -1 + i*n).
// ---------------------------------------------------------------------------
__device__ __forceinline__ bool load_consts4(const float* A_log, const float* A_im,
        const float* B_param, int hnb,
        float* Are, float* Aim, float* BAr, float* BAi) {
    #pragma unroll
    for (int j = 0; j < 4; ++j) {
        int hn = hnb + j;
        Are[j] = -__expf(A_log[hn]);
        Aim[j] = A_im[hn];
        float Bre = B_param[2 * hn];
        float Bim = B_param[2 * hn + 1];
        float inv = __builtin_amdgcn_rcpf(Are[j] * Are[j] + Aim[j] * Aim[j]);
        BAr[j] = (Bre * Are[j] + Bim * Aim[j]) * inv;   // Bc*conj(A)/|A|^2
        BAi[j] = (Bim * Are[j] - Bre * Aim[j]) * inv;
    }
    float d1 = Aim[1] - Aim[0], d2 = Aim[2] - Aim[1], d3 = Aim[3] - Aim[2];
    return (Are[1] == Are[0]) && (Are[2] == Are[0]) && (Are[3] == Are[0]) &&
           (d1 == d2) && (d2 == d3);
}

// ---------------------------------------------------------------------------
// Kernel 1: dt = softplus(u@xprojT@dtwT + b); writes du[l][h] = (dt, u/dt).
// ---------------------------------------------------------------------------
__global__ __launch_bounds__(256) void k_dt(const float* __restrict__ u,
                                            const float* __restrict__ xproj_w,
                                            const float* __restrict__ dt_w,
                                            const float* __restrict__ dt_b,
                                            float2* __restrict__ du_out) {
    __shared__ float u_s[8][Hd];
    __shared__ float dtu_s[8][Rd];
    const int t = threadIdx.x;
    const int l0 = blockIdx.x * 8;

    #pragma unroll
    for (int i = 0; i < 16; ++i) {
        int idx = t + i * 256;
        ((float*)u_s)[idx] = u[l0 * Hd + idx];
    }
    __syncthreads();

    const int r = t >> 3;
    const int j = t & 7;
    float part[8];
    #pragma unroll
    for (int l = 0; l < 8; ++l) part[l] = 0.f;
    for (int k = 0; k < 64; ++k) {
        float w = xproj_w[r * Hd + k * 8 + j];
        #pragma unroll
        for (int l = 0; l < 8; ++l) part[l] = fmaf(u_s[l][k * 8 + j], w, part[l]);
    }
    #pragma unroll
    for (int off = 1; off < 8; off <<= 1) {
        #pragma unroll
        for (int l = 0; l < 8; ++l) part[l] += __shfl_xor(part[l], off);
    }
    if (j == 0) {
        #pragma unroll
        for (int l = 0; l < 8; ++l) dtu_s[l][r] = part[l];
    }
    __syncthreads();

    #pragma unroll
    for (int hb = 0; hb < 2; ++hb) {
        int h = hb * 256 + t;
        float bias = dt_b[h];
        float acc[8];
        #pragma unroll
        for (int l = 0; l < 8; ++l) acc[l] = bias;
        #pragma unroll
        for (int rb = 0; rb < 8; ++rb) {
            float4 w = *(const float4*)&dt_w[h * Rd + rb * 4];
            #pragma unroll
            for (int l = 0; l < 8; ++l) {
                acc[l] = fmaf(dtu_s[l][rb * 4 + 0], w.x, acc[l]);
                acc[l] = fmaf(dtu_s[l][rb * 4 + 1], w.y, acc[l]);
                acc[l] = fmaf(dtu_s[l][rb * 4 + 2], w.z, acc[l]);
                acc[l] = fmaf(dtu_s[l][rb * 4 + 3], w.w, acc[l]);
            }
        }
        #pragma unroll
        for (int l = 0; l < 8; ++l) {
            float x = acc[l];
            float sp = fmaxf(x, 0.f) + log1pf(__expf(-fabsf(x)));  // softplus
            float uv = u_s[l][h];
            float us = uv * __builtin_amdgcn_rcpf(fmaxf(sp, 1e-30f));
            du_out[(l0 + l) * Hd + h] = make_float2(sp, us);
        }
    }
}

// ---------------------------------------------------------------------------
// Kernel 2: per-chunk local scan (h0=0). Emits:
//   PS[c][chain] = (P.re, P.im, S.re, S.im)        (chunk aggregate)
//   y1T[l][h]    = (Re(C*S_local_l) + D*u_l, T_l)  (partial y + incl. sum-dt)
// du staged in 4 software-pipelined batches of 8 (b0/b1 double buffer, all
// static indexing) -> VGPR diet (was 64 regs of staging) + loads overlap the
// serial recurrence of the previous batch.
// ---------------------------------------------------------------------------
__global__ __launch_bounds__(256) void k_chunk(const float2* __restrict__ du,
        const float* __restrict__ A_log, const float* __restrict__ A_im,
        const float* __restrict__ B_param, const float* __restrict__ C_param,
        const float* __restrict__ Dp,
        float4* __restrict__ PS, float2* __restrict__ y1T) {
    const int t = threadIdx.x;
    const int q = t & 3;
    const int hh = blockIdx.y * 64 + (t >> 2);
    const int c = blockIdx.x;
    const int hnb = hh * N2d + q * 4;
    const int lbase = c * CLEN;

    float Are[4], Aim[4], BAr[4], BAi[4], Cre[4], Cim[4];
    const bool fast = load_consts4(A_log, A_im, B_param, hnb, Are, Aim, BAr, BAi);
    #pragma unroll
    for (int jj = 0; jj < 4; ++jj) {
        Cre[jj] = C_param[2 * (hnb + jj)];
        Cim[jj] = C_param[2 * (hnb + jj) + 1];
    }
    const float Dv = Dp[hh];

    float sr[4] = {0.f, 0.f, 0.f, 0.f}, si[4] = {0.f, 0.f, 0.f, 0.f};
    float sdt = 0.f;

    float2 b0[8], b1[8];

    #define LOADB(buf, bb)                                                     \
        { _Pragma("unroll")                                                    \
          for (int k = 0; k < 8; ++k)                                          \
              buf[k] = du[(lbase + (bb) * 8 + k) * Hd + hh]; }

    if (fast) {
        const float Are0 = Are[0], Aim0 = Aim[0], dA = Aim[1] - Aim[0];
        #define STEPF(buf, bb)                                                 \
            { _Pragma("unroll")                                                \
              for (int k = 0; k < 8; ++k) {                                    \
                int l = lbase + (bb) * 8 + k;                                  \
                float dtv = buf[k].x, us = buf[k].y;                           \
                sdt += dtv;                                                    \
                float er = __expf(dtv * Are0);                                 \
                float s0, c0, sd, cd;                                          \
                __sincosf(dtv * Aim0, &s0, &c0);                               \
                __sincosf(dtv * dA, &sd, &cd);                                 \
                float ar = er * c0, ai = er * s0;                              \
                float yv = 0.f;                                                \
                _Pragma("unroll")                                              \
                for (int jj = 0; jj < 4; ++jj) {                               \
                    float gr = fmaf(ar, us, -us);                              \
                    float gi = ai * us;                                        \
                    float nr = fmaf(ar, sr[jj], fmaf(-ai, si[jj],              \
                                 fmaf(gr, BAr[jj], -gi * BAi[jj])));           \
                    float ni = fmaf(ar, si[jj], fmaf( ai, sr[jj],              \
                                 fmaf(gr, BAi[jj],  gi * BAr[jj])));           \
                    sr[jj] = nr; si[jj] = ni;                                  \
                    yv = fmaf(nr, Cre[jj], fmaf(-ni, Cim[jj], yv));            \
                    if (jj < 3) {                                              \
                        float tr = fmaf(ar, cd, -ai * sd);                     \
                        ai = fmaf(ai, cd, ar * sd);                            \
                        ar = tr;                                               \
                    }                                                          \
                }                                                              \
                yv += __shfl_xor(yv, 1);                                       \
                yv += __shfl_xor(yv, 2);                                       \
                if (q == 0)                                                    \
                    y1T[l * Hd + hh] = make_float2(fmaf(dtv * us, Dv, yv), sdt);\
              } }
        LOADB(b0, 0);
        LOADB(b1, 1); STEPF(b0, 0);
        LOADB(b0, 2); STEPF(b1, 1);
        LOADB(b1, 3); STEPF(b0, 2);
        STEPF(b1, 3);
        #undef STEPF
    } else {
        #define STEPS(buf, bb)                                                 \
            { _Pragma("unroll")                                                \
              for (int k = 0; k < 8; ++k) {                                    \
                int l = lbase + (bb) * 8 + k;                                  \
                float dtv = buf[k].x, us = buf[k].y;                           \
                sdt += dtv;                                                    \
                float yv = 0.f;                                                \
                _Pragma("unroll")                                              \
                for (int jj = 0; jj < 4; ++jj) {                               \
                    float er = __expf(dtv * Are[jj]);                          \
                    float s, cc;                                               \
                    __sincosf(dtv * Aim[jj], &s, &cc);                         \
                    float ar = er * cc, ai = er * s;                           \
                    float gr = fmaf(ar, us, -us);                              \
                    float gi = ai * us;                                        \
                    float nr = fmaf(ar, sr[jj], fmaf(-ai, si[jj],              \
                                 fmaf(gr, BAr[jj], -gi * BAi[jj])));           \
                    float ni = fmaf(ar, si[jj], fmaf( ai, sr[jj],              \
                                 fmaf(gr, BAi[jj],  gi * BAr[jj])));           \
                    sr[jj] = nr; si[jj] = ni;                                  \
                    yv = fmaf(nr, Cre[jj], fmaf(-ni, Cim[jj], yv));            \
                }                                                              \
                yv += __shfl_xor(yv, 1);                                       \
                yv += __shfl_xor(yv, 2);                                       \
                if (q == 0)                                                    \
                    y1T[l * Hd + hh] = make_float2(fmaf(dtv * us, Dv, yv), sdt);\
              } }
        LOADB(b0, 0);
        LOADB(b1, 1); STEPS(b0, 0);
        LOADB(b0, 2); STEPS(b1, 1);
        LOADB(b1, 3); STEPS(b0, 2);
        STEPS(b1, 3);
        #undef STEPS
    }
    #undef LOADB

    int base = c * NCH + hnb;
    #pragma unroll
    for (int jj = 0; jj < 4; ++jj) {
        float er = __expf(sdt * Are[jj]);
        float s, cc;
        __sincosf(sdt * Aim[jj], &s, &cc);
        PS[base + jj] = make_float4(er * cc, er * s, sr[jj], si[jj]);
    }
}

// ---------------------------------------------------------------------------
// Kernel 3a: per-(chain, group) combine over NGRP=16 chunks.
// Writes EXCLUSIVE in-group prefix IP[c] = (Pcum, Ilocal) and group agg Gps.
// ---------------------------------------------------------------------------
__global__ __launch_bounds__(256) void k_group(const float4* __restrict__ PS,
                                               float4* __restrict__ IP,
                                               float4* __restrict__ Gps) {
    int idx = blockIdx.x * 256 + threadIdx.x;   // 0..65535
    int chain = idx & (NCH - 1);
    int g = idx >> 13;                          // 0..7
    float pr = 1.f, pi = 0.f, hr = 0.f, hi = 0.f;
    #pragma unroll
    for (int half = 0; half < 2; ++half) {
        float4 ps[8];
        #pragma unroll
        for (int i = 0; i < 8; ++i)
            ps[i] = PS[(g * NGRP + half * 8 + i) * NCH + chain];
        #pragma unroll
        for (int i = 0; i < 8; ++i) {
            int c = g * NGRP + half * 8 + i;
            IP[c * NCH + chain] = make_float4(pr, pi, hr, hi);
            float nhr = fmaf(ps[i].x, hr, fmaf(-ps[i].y, hi, ps[i].z));
            float nhi = fmaf(ps[i].x, hi, fmaf( ps[i].y, hr, ps[i].w));
            float npr = fmaf(ps[i].x, pr, -ps[i].y * pi);
            float npi = fmaf(ps[i].x, pi,  ps[i].y * pr);
            hr = nhr; hi = nhi; pr = npr; pi = npi;
        }
    }
    Gps[g * NCH + chain] = make_float4(pr, pi, hr, hi);
}

// ---------------------------------------------------------------------------
// Kernel 3b: exclusive scan of the 8 group aggregates per chain -> H0g.
// ---------------------------------------------------------------------------
__global__ __launch_bounds__(256) void k_gscan(const float4* __restrict__ Gps,
                                               float2* __restrict__ H0g) {
    int chain = blockIdx.x * 256 + threadIdx.x;  // 0..8191
    float4 gp[NGROUPS];
    #pragma unroll
    for (int i = 0; i < NGROUPS; ++i)
        gp[i] = Gps[i * NCH + chain];
    float hr = 0.f, hi = 0.f;
    #pragma unroll
    for (int i = 0; i < NGROUPS; ++i) {
        H0g[i * NCH + chain] = make_float2(hr, hi);
        float nr = fmaf(gp[i].x, hr, fmaf(-gp[i].y, hi, gp[i].z));
        float ni = fmaf(gp[i].x, hi, fmaf( gp[i].y, hr, gp[i].w));
        hr = nr; hi = ni;
    }
}

// ---------------------------------------------------------------------------
// Kernel 4: correction pass. Block = (chunk c, 64-h group). Stages the
// per-(c,chain) weight W = C*(Ilocal + Pcum*H0g) into LDS ONCE (coalesced,
// reused by all 32 l's), plus Are/Aim rows. Each thread owns one h (lane=h ->
// coalesced y1T/out) x 8 l's with W-row/A-row hoisted into registers:
//   y = y1 + Re( sum_n exp(A_n*T_l) * W_n )
// ---------------------------------------------------------------------------
__global__ __launch_bounds__(256) void k_corr(const float2* __restrict__ y1T,
        const float* __restrict__ A_log, const float* __restrict__ A_im,
        const float* __restrict__ C_param, const float4* __restrict__ IP,
        const float2* __restrict__ H0g, float* __restrict__ out) {
    __shared__ float2 W_s[64][17];   // [h_local][n], pad -> 2-way (free)
    __shared__ float Ar_s[64][17];
    __shared__ float Ai_s[64][17];
    const int t = threadIdx.x;
    const int c = blockIdx.x;        // chunk
    const int hg = blockIdx.y;       // h-group (64 h)
    const int g = c >> 4;            // NGRP = 16
    const int chain0 = hg * 1024;    // 64 h * 16 n contiguous chains

    // ---- cooperative staging: 4 contiguous chains per thread ----
    #pragma unroll
    for (int i = 0; i < 4; ++i) {
        int cl = t * 4 + i;                       // 0..1023
        float4 ip = IP[c * NCH + chain0 + cl];    // (Pcum, Ilocal)
        float2 hgv = H0g[g * NCH + chain0 + cl];
        float h0r = fmaf(ip.x, hgv.x, fmaf(-ip.y, hgv.y, ip.z));
        float h0i = fmaf(ip.x, hgv.y, fmaf( ip.y, hgv.x, ip.w));
        float Cr = C_param[2 * (chain0 + cl)];
        float Ci = C_param[2 * (chain0 + cl) + 1];
        int hl = cl >> 4, n = cl & 15;
        W_s[hl][n] = make_float2(fmaf(Cr, h0r, -Ci * h0i),
                                 fmaf(Cr, h0i,  Ci * h0r));
        Ar_s[hl][n] = -__expf(A_log[chain0 + cl]);
        Ai_s[hl][n] = A_im[chain0 + cl];
    }
    __syncthreads();

    // ---- per-thread: one h, 8 l's ----
    const int hl = t & 63;
    const int h = hg * 64 + hl;
    const int lb = t >> 6;                        // 0..3
    const int l0 = c * CLEN + lb * 8;

    float2 yt[8];
    #pragma unroll
    for (int k = 0; k < 8; ++k) yt[k] = y1T[(l0 + k) * Hd + h];

    float2 w[N2d];
    float are[N2d], aim[N2d];
    #pragma unroll
    for (int n = 0; n < N2d; ++n) {
        w[n] = W_s[hl][n];
        are[n] = Ar_s[hl][n];
        aim[n] = Ai_s[hl][n];
    }
    float dA = aim[1] - aim[0];
    bool fast = true;
    #pragma unroll
    for (int n = 1; n < N2d; ++n)
        fast = fast && (are[n] == are[0]) && (aim[n] - aim[n - 1] == dA);

    if (fast) {
        const float Are0 = are[0], Aim0 = aim[0];
        #pragma unroll
        for (int k = 0; k < 8; ++k) {
            float T = yt[k].y;
            float er = __expf(Are0 * T);
            float s0, c0, sd, cd;
            __sincosf(Aim0 * T, &s0, &c0);
            __sincosf(dA * T, &sd, &cd);
            float ar = er * c0, ai = er * s0;
            float corr = 0.f;
            #pragma unroll
            for (int n = 0; n < N2d; ++n) {
                corr = fmaf(ar, w[n].x, fmaf(-ai, w[n].y, corr));
                if (n < N2d - 1) {
                    float tr = fmaf(ar, cd, -ai * sd);
                    ai = fmaf(ai, cd, ar * sd);
                    ar = tr;
                }
            }
            out[(l0 + k) * Hd + h] = yt[k].x + corr;
        }
    } else {
        #pragma unroll
        for (int k = 0; k < 8; ++k) {
            float T = yt[k].y;
            float corr = 0.f;
            #pragma unroll
            for (int n = 0; n < N2d; ++n) {
                float er = __expf(are[n] * T);
                float s, cc;
                __sincosf(aim[n] * T, &s, &cc);
                corr = fmaf(er * cc, w[n].x, fmaf(-er * s, w[n].y, corr));
            }
            out[(l0 + k) * Hd + h] = yt[k].x + corr;
        }
    }
}

extern "C" void kernel_launch(void* const* d_in, const int* in_sizes, int n_in,
                              void* d_out, int out_size, void* d_ws, size_t ws_size,
                              hipStream_t stream) {
    const float* u        = (const float*)d_in[0];
    const float* A_log    = (const float*)d_in[1];
    const float* A_im     = (const float*)d_in[2];
    const float* B_param  = (const float*)d_in[3];
    const float* C_param  = (const float*)d_in[4];
    const float* Dp       = (const float*)d_in[5];
    const float* dt_w     = (const float*)d_in[6];
    const float* dt_b     = (const float*)d_in[7];
    const float* xproj_w  = (const float*)d_in[8];

    // ws layout: du[L*H f2] | PS[NCHUNK*NCH f4] | IP[NCHUNK*NCH f4]
    //          | Gps[NGROUPS*NCH f4] | H0g[NGROUPS*NCH f2] | y1T[L*H f2]
    float2* du  = (float2*)d_ws;
    float4* PS  = (float4*)(du + (size_t)Ld * Hd);
    float4* IP  = PS + (size_t)NCHUNK * NCH;
    float4* Gps = IP + (size_t)NCHUNK * NCH;
    float2* H0g = (float2*)(Gps + (size_t)NGROUPS * NCH);
    float2* y1T = H0g + (size_t)NGROUPS * NCH;
    float*  out = (float*)d_out;

    k_dt<<<Ld / 8, 256, 0, stream>>>(u, xproj_w, dt_w, dt_b, du);
    dim3 g2(NCHUNK, Hd / 64);
    k_chunk<<<g2, 256, 0, stream>>>(du, A_log, A_im, B_param, C_param, Dp, PS, y1T);
    k_group<<<(NCH * NGROUPS) / 256, 256, 0, stream>>>(PS, IP, Gps);
    k_gscan<<<NCH / 256, 256, 0, stream>>>(Gps, H0g);
    k_corr<<<g2, 256, 0, stream>>>(y1T, A_log, A_im, C_param, IP, H0g, out);
}

// Round 9
// 134.262 us; speedup vs baseline: 2.1055x; 1.0371x over previous
//
#include <hip/hip_runtime.h>

#define Hd 512
#define N2d 16
#define Rd 32
#define Ld 4096
#define NCHUNK 128
#define CLEN (Ld / NCHUNK)        // 32
#define NCH (Hd * N2d)            // 8192 chains
#define NGRP 16                   // chunks per prefix group
#define NGROUPS (NCHUNK / NGRP)   // 8

// ---------------------------------------------------------------------------
// Per-thread constant setup: 4 consecutive n of one h. fast == true when Are
// uniform and Aim arithmetic across the 4 (true for S4D init A = -1 + i*n).
// ---------------------------------------------------------------------------
__device__ __forceinline__ bool load_consts4(const float* A_log, const float* A_im,
        const float* B_param, int hnb,
        float* Are, float* Aim, float* BAr, float* BAi) {
    #pragma unroll
    for (int j = 0; j < 4; ++j) {
        int hn = hnb + j;
        Are[j] = -__expf(A_log[hn]);
        Aim[j] = A_im[hn];
        float Bre = B_param[2 * hn];
        float Bim = B_param[2 * hn + 1];
        float inv = __builtin_amdgcn_rcpf(Are[j] * Are[j] + Aim[j] * Aim[j]);
        BAr[j] = (Bre * Are[j] + Bim * Aim[j]) * inv;   // Bc*conj(A)/|A|^2
        BAi[j] = (Bim * Are[j] - Bre * Aim[j]) * inv;
    }
    float d1 = Aim[1] - Aim[0], d2 = Aim[2] - Aim[1], d3 = Aim[3] - Aim[2];
    return (Are[1] == Are[0]) && (Are[2] == Are[0]) && (Are[3] == Are[0]) &&
           (d1 == d2) && (d2 == d3);
}

// ---------------------------------------------------------------------------
// Kernel 1: dt = softplus(u@xprojT@dtwT + b); writes du[l][h] = (dt, u/dt).
// ---------------------------------------------------------------------------
__global__ __launch_bounds__(256) void k_dt(const float* __restrict__ u,
                                            const float* __restrict__ xproj_w,
                                            const float* __restrict__ dt_w,
                                            const float* __restrict__ dt_b,
                                            float2* __restrict__ du_out) {
    __shared__ float u_s[8][Hd];
    __shared__ float dtu_s[8][Rd];
    const int t = threadIdx.x;
    const int l0 = blockIdx.x * 8;

    #pragma unroll
    for (int i = 0; i < 16; ++i) {
        int idx = t + i * 256;
        ((float*)u_s)[idx] = u[l0 * Hd + idx];
    }
    __syncthreads();

    const int r = t >> 3;
    const int j = t & 7;
    float part[8];
    #pragma unroll
    for (int l = 0; l < 8; ++l) part[l] = 0.f;
    for (int k = 0; k < 64; ++k) {
        float w = xproj_w[r * Hd + k * 8 + j];
        #pragma unroll
        for (int l = 0; l < 8; ++l) part[l] = fmaf(u_s[l][k * 8 + j], w, part[l]);
    }
    #pragma unroll
    for (int off = 1; off < 8; off <<= 1) {
        #pragma unroll
        for (int l = 0; l < 8; ++l) part[l] += __shfl_xor(part[l], off);
    }
    if (j == 0) {
        #pragma unroll
        for (int l = 0; l < 8; ++l) dtu_s[l][r] = part[l];
    }
    __syncthreads();

    #pragma unroll
    for (int hb = 0; hb < 2; ++hb) {
        int h = hb * 256 + t;
        float bias = dt_b[h];
        float acc[8];
        #pragma unroll
        for (int l = 0; l < 8; ++l) acc[l] = bias;
        #pragma unroll
        for (int rb = 0; rb < 8; ++rb) {
            float4 w = *(const float4*)&dt_w[h * Rd + rb * 4];
            #pragma unroll
            for (int l = 0; l < 8; ++l) {
                acc[l] = fmaf(dtu_s[l][rb * 4 + 0], w.x, acc[l]);
                acc[l] = fmaf(dtu_s[l][rb * 4 + 1], w.y, acc[l]);
                acc[l] = fmaf(dtu_s[l][rb * 4 + 2], w.z, acc[l]);
                acc[l] = fmaf(dtu_s[l][rb * 4 + 3], w.w, acc[l]);
            }
        }
        #pragma unroll
        for (int l = 0; l < 8; ++l) {
            float x = acc[l];
            float sp = fmaxf(x, 0.f) + log1pf(__expf(-fabsf(x)));  // softplus
            float uv = u_s[l][h];
            float us = uv * __builtin_amdgcn_rcpf(fmaxf(sp, 1e-30f));
            du_out[(l0 + l) * Hd + h] = make_float2(sp, us);
        }
    }
}

// ---------------------------------------------------------------------------
// Kernel 2: per-chunk local scan (h0=0). Emits:
//   PS[c][chain] = (P.re, P.im, S.re, S.im)        (chunk aggregate)
//   y1T[l][h]    = (Re(C*S_local_l) + D*u_l, T_l)  (partial y + incl. sum-dt)
// du staged in 4 software-pipelined batches of 8 (b0/b1 double buffer).
// ---------------------------------------------------------------------------
__global__ __launch_bounds__(256) void k_chunk(const float2* __restrict__ du,
        const float* __restrict__ A_log, const float* __restrict__ A_im,
        const float* __restrict__ B_param, const float* __restrict__ C_param,
        const float* __restrict__ Dp,
        float4* __restrict__ PS, float2* __restrict__ y1T) {
    const int t = threadIdx.x;
    const int q = t & 3;
    const int hh = blockIdx.y * 64 + (t >> 2);
    const int c = blockIdx.x;
    const int hnb = hh * N2d + q * 4;
    const int lbase = c * CLEN;

    float Are[4], Aim[4], BAr[4], BAi[4], Cre[4], Cim[4];
    const bool fast = load_consts4(A_log, A_im, B_param, hnb, Are, Aim, BAr, BAi);
    #pragma unroll
    for (int jj = 0; jj < 4; ++jj) {
        Cre[jj] = C_param[2 * (hnb + jj)];
        Cim[jj] = C_param[2 * (hnb + jj) + 1];
    }
    const float Dv = Dp[hh];

    float sr[4] = {0.f, 0.f, 0.f, 0.f}, si[4] = {0.f, 0.f, 0.f, 0.f};
    float sdt = 0.f;

    float2 b0[8], b1[8];

    #define LOADB(buf, bb)                                                     \
        { _Pragma("unroll")                                                    \
          for (int k = 0; k < 8; ++k)                                          \
              buf[k] = du[(lbase + (bb) * 8 + k) * Hd + hh]; }

    if (fast) {
        const float Are0 = Are[0], Aim0 = Aim[0], dA = Aim[1] - Aim[0];
        #define STEPF(buf, bb)                                                 \
            { _Pragma("unroll")                                                \
              for (int k = 0; k < 8; ++k) {                                    \
                int l = lbase + (bb) * 8 + k;                                  \
                float dtv = buf[k].x, us = buf[k].y;                           \
                sdt += dtv;                                                    \
                float er = __expf(dtv * Are0);                                 \
                float s0, c0, sd, cd;                                          \
                __sincosf(dtv * Aim0, &s0, &c0);                               \
                __sincosf(dtv * dA, &sd, &cd);                                 \
                float ar = er * c0, ai = er * s0;                              \
                float yv = 0.f;                                                \
                _Pragma("unroll")                                              \
                for (int jj = 0; jj < 4; ++jj) {                               \
                    float gr = fmaf(ar, us, -us);                              \
                    float gi = ai * us;                                        \
                    float nr = fmaf(ar, sr[jj], fmaf(-ai, si[jj],              \
                                 fmaf(gr, BAr[jj], -gi * BAi[jj])));           \
                    float ni = fmaf(ar, si[jj], fmaf( ai, sr[jj],              \
                                 fmaf(gr, BAi[jj],  gi * BAr[jj])));           \
                    sr[jj] = nr; si[jj] = ni;                                  \
                    yv = fmaf(nr, Cre[jj], fmaf(-ni, Cim[jj], yv));            \
                    if (jj < 3) {                                              \
                        float tr = fmaf(ar, cd, -ai * sd);                     \
                        ai = fmaf(ai, cd, ar * sd);                            \
                        ar = tr;                                               \
                    }                                                          \
                }                                                              \
                yv += __shfl_xor(yv, 1);                                       \
                yv += __shfl_xor(yv, 2);                                       \
                if (q == 0)                                                    \
                    y1T[l * Hd + hh] = make_float2(fmaf(dtv * us, Dv, yv), sdt);\
              } }
        LOADB(b0, 0);
        LOADB(b1, 1); STEPF(b0, 0);
        LOADB(b0, 2); STEPF(b1, 1);
        LOADB(b1, 3); STEPF(b0, 2);
        STEPF(b1, 3);
        #undef STEPF
    } else {
        #define STEPS(buf, bb)                                                 \
            { _Pragma("unroll")                                                \
              for (int k = 0; k < 8; ++k) {                                    \
                int l = lbase + (bb) * 8 + k;                                  \
                float dtv = buf[k].x, us = buf[k].y;                           \
                sdt += dtv;                                                    \
                float yv = 0.f;                                                \
                _Pragma("unroll")                                              \
                for (int jj = 0; jj < 4; ++jj) {                               \
                    float er = __expf(dtv * Are[jj]);                          \
                    float s, cc;                                               \
                    __sincosf(dtv * Aim[jj], &s, &cc);                         \
                    float ar = er * cc, ai = er * s;                           \
                    float gr = fmaf(ar, us, -us);                              \
                    float gi = ai * us;                                        \
                    float nr = fmaf(ar, sr[jj], fmaf(-ai, si[jj],              \
                                 fmaf(gr, BAr[jj], -gi * BAi[jj])));           \
                    float ni = fmaf(ar, si[jj], fmaf( ai, sr[jj],              \
                                 fmaf(gr, BAi[jj],  gi * BAr[jj])));           \
                    sr[jj] = nr; si[jj] = ni;                                  \
                    yv = fmaf(nr, Cre[jj], fmaf(-ni, Cim[jj], yv));            \
                }                                                              \
                yv += __shfl_xor(yv, 1);                                       \
                yv += __shfl_xor(yv, 2);                                       \
                if (q == 0)                                                    \
                    y1T[l * Hd + hh] = make_float2(fmaf(dtv * us, Dv, yv), sdt);\
              } }
        LOADB(b0, 0);
        LOADB(b1, 1); STEPS(b0, 0);
        LOADB(b0, 2); STEPS(b1, 1);
        LOADB(b1, 3); STEPS(b0, 2);
        STEPS(b1, 3);
        #undef STEPS
    }
    #undef LOADB

    int base = c * NCH + hnb;
    #pragma unroll
    for (int jj = 0; jj < 4; ++jj) {
        float er = __expf(sdt * Are[jj]);
        float s, cc;
        __sincosf(sdt * Aim[jj], &s, &cc);
        PS[base + jj] = make_float4(er * cc, er * s, sr[jj], si[jj]);
    }
}

// ---------------------------------------------------------------------------
// Kernel 3: fused prefix-combine (replaces k_group + k_gscan + the IP/H0g
// round-trip). Block = {32 chains x 8 groups} (256 threads). Each thread:
//   (1) aggregates its group's 16 PS entries (kept in registers),
//   (2) LDS-exchanges the 8 group aggregates per chain, computes its
//       exclusive cross-group prefix locally (<=7 complex FMA),
//   (3) walks its 16 chunks emitting W[c][chain] = C * h0(c)  (float2).
// PS read exactly once; W is the only output (8.4 MB vs IP's 33.6 round-trip).
// ---------------------------------------------------------------------------
__global__ __launch_bounds__(256) void k_comb(const float4* __restrict__ PS,
                                              const float* __restrict__ C_param,
                                              float2* __restrict__ W) {
    __shared__ float4 agg_s[32][NGROUPS + 1];   // [chain_l][g], pad
    const int t = threadIdx.x;
    const int g = t >> 5;                       // 0..7 (uniform per half-wave)
    const int cl = t & 31;
    const int chain = blockIdx.x * 32 + cl;

    float4 ps[NGRP];
    #pragma unroll
    for (int i = 0; i < NGRP; ++i)
        ps[i] = PS[(g * NGRP + i) * NCH + chain];

    float pr = 1.f, pi = 0.f, hr = 0.f, hi = 0.f;
    #pragma unroll
    for (int i = 0; i < NGRP; ++i) {
        float nhr = fmaf(ps[i].x, hr, fmaf(-ps[i].y, hi, ps[i].z));
        float nhi = fmaf(ps[i].x, hi, fmaf( ps[i].y, hr, ps[i].w));
        float npr = fmaf(ps[i].x, pr, -ps[i].y * pi);
        float npi = fmaf(ps[i].x, pi,  ps[i].y * pr);
        hr = nhr; hi = nhi; pr = npr; pi = npi;
    }
    agg_s[cl][g] = make_float4(pr, pi, hr, hi);
    __syncthreads();

    // exclusive cross-group prefix (g is uniform across each 32-lane slice)
    float Hr = 0.f, Hi = 0.f;
    for (int j = 0; j < g; ++j) {
        float4 a = agg_s[cl][j];
        float nr = fmaf(a.x, Hr, fmaf(-a.y, Hi, a.z));
        float ni = fmaf(a.x, Hi, fmaf( a.y, Hr, a.w));
        Hr = nr; Hi = ni;
    }

    const float Cr = C_param[2 * chain];
    const float Ci = C_param[2 * chain + 1];
    #pragma unroll
    for (int i = 0; i < NGRP; ++i) {
        int c = g * NGRP + i;
        W[c * NCH + chain] = make_float2(fmaf(Cr, Hr, -Ci * Hi),
                                         fmaf(Cr, Hi,  Ci * Hr));
        float nr = fmaf(ps[i].x, Hr, fmaf(-ps[i].y, Hi, ps[i].z));
        float ni = fmaf(ps[i].x, Hi, fmaf( ps[i].y, Hr, ps[i].w));
        Hr = nr; Hi = ni;
    }
}

// ---------------------------------------------------------------------------
// Kernel 4: correction pass. No LDS, no sync. Thread owns one h (coalesced
// y1T/out) x 8 l's; reads its W row (128 B contiguous) and A rows (L2-hot):
//   y = y1 + Re( sum_n exp(A_n*T_l) * W_n )
// ---------------------------------------------------------------------------
__global__ __launch_bounds__(256) void k_corr(const float2* __restrict__ y1T,
        const float* __restrict__ A_log, const float* __restrict__ A_im,
        const float2* __restrict__ W, float* __restrict__ out) {
    const int t = threadIdx.x;
    const int c = blockIdx.x;        // chunk
    const int hl = t & 63;
    const int h = blockIdx.y * 64 + hl;
    const int lb = t >> 6;           // 0..3
    const int l0 = c * CLEN + lb * 8;
    const int hn0 = h * N2d;

    float2 yt[8];
    #pragma unroll
    for (int k = 0; k < 8; ++k) yt[k] = y1T[(l0 + k) * Hd + h];

    float2 w[N2d];
    #pragma unroll
    for (int n = 0; n < N2d; ++n) w[n] = W[c * NCH + hn0 + n];

    float are[N2d], aim[N2d];
    #pragma unroll
    for (int n = 0; n < N2d; ++n) {
        are[n] = -__expf(A_log[hn0 + n]);
        aim[n] = A_im[hn0 + n];
    }
    float dA = aim[1] - aim[0];
    bool fast = true;
    #pragma unroll
    for (int n = 1; n < N2d; ++n)
        fast = fast && (are[n] == are[0]) && (aim[n] - aim[n - 1] == dA);

    if (fast) {
        const float Are0 = are[0], Aim0 = aim[0];
        #pragma unroll
        for (int k = 0; k < 8; ++k) {
            float T = yt[k].y;
            float er = __expf(Are0 * T);
            float s0, c0, sd, cd;
            __sincosf(Aim0 * T, &s0, &c0);
            __sincosf(dA * T, &sd, &cd);
            float ar = er * c0, ai = er * s0;
            float corr = 0.f;
            #pragma unroll
            for (int n = 0; n < N2d; ++n) {
                corr = fmaf(ar, w[n].x, fmaf(-ai, w[n].y, corr));
                if (n < N2d - 1) {
                    float tr = fmaf(ar, cd, -ai * sd);
                    ai = fmaf(ai, cd, ar * sd);
                    ar = tr;
                }
            }
            out[(l0 + k) * Hd + h] = yt[k].x + corr;
        }
    } else {
        #pragma unroll
        for (int k = 0; k < 8; ++k) {
            float T = yt[k].y;
            float corr = 0.f;
            #pragma unroll
            for (int n = 0; n < N2d; ++n) {
                float er = __expf(are[n] * T);
                float s, cc;
                __sincosf(aim[n] * T, &s, &cc);
                corr = fmaf(er * cc, w[n].x, fmaf(-er * s, w[n].y, corr));
            }
            out[(l0 + k) * Hd + h] = yt[k].x + corr;
        }
    }
}

extern "C" void kernel_launch(void* const* d_in, const int* in_sizes, int n_in,
                              void* d_out, int out_size, void* d_ws, size_t ws_size,
                              hipStream_t stream) {
    const float* u        = (const float*)d_in[0];
    const float* A_log    = (const float*)d_in[1];
    const float* A_im     = (const float*)d_in[2];
    const float* B_param  = (const float*)d_in[3];
    const float* C_param  = (const float*)d_in[4];
    const float* Dp       = (const float*)d_in[5];
    const float* dt_w     = (const float*)d_in[6];
    const float* dt_b     = (const float*)d_in[7];
    const float* xproj_w  = (const float*)d_in[8];

    // ws layout: du[L*H f2] | PS[NCHUNK*NCH f4] | W[NCHUNK*NCH f2] | y1T[L*H f2]
    float2* du  = (float2*)d_ws;
    float4* PS  = (float4*)(du + (size_t)Ld * Hd);
    float2* W   = (float2*)(PS + (size_t)NCHUNK * NCH);
    float2* y1T = W + (size_t)NCHUNK * NCH;
    float*  out = (float*)d_out;

    k_dt<<<Ld / 8, 256, 0, stream>>>(u, xproj_w, dt_w, dt_b, du);
    dim3 g2(NCHUNK, Hd / 64);
    k_chunk<<<g2, 256, 0, stream>>>(du, A_log, A_im, B_param, C_param, Dp, PS, y1T);
    k_comb<<<NCH / 32, 256, 0, stream>>>(PS, C_param, W);
    k_corr<<<g2, 256, 0, stream>>>(y1T, A_log, A_im, W, out);
}